// Round 2
// baseline (99.275 us; speedup 1.0000x reference)
//
#include <hip/hip_runtime.h>

#define TILE 256          // rows per block
#define TFLOATS (TILE * 25)   // 6400 floats = 25.6 KB

__global__ __launch_bounds__(256) void returning_rate_kernel(
    const float* __restrict__ pred, const float* __restrict__ mask,
    float* __restrict__ out, int B) {
  __shared__ float tile[TFLOATS];
  const int t = threadIdx.x;
  const long long blockRow = (long long)blockIdx.x * TILE;
  const bool full = (blockRow + TILE <= (long long)B);
  const bool active = (blockRow + t) < (long long)B;

  // ---------- stage pred tile (coalesced float4) ----------
  if (full) {
    const float4* src = (const float4*)(pred + blockRow * 25);  // 6400*bid floats -> 16B aligned
    float4* dst = (float4*)tile;
    #pragma unroll
    for (int k = 0; k < 7; ++k) {
      int i = k * 256 + t;
      if (i < TFLOATS / 4) dst[i] = src[i];
    }
  } else {
    const float* src = pred + blockRow * 25;
    int n = (int)((long long)B - blockRow) * 25;
    for (int i = t; i < n; i += 256) tile[i] = src[i];
  }
  __syncthreads();

  // ---------- extract pred row (stride 25 -> 2-way bank alias, free) ----------
  float p40=0,p41=0,p42=0,p43=0,p44=0,p31=0,p32=0,p33=0,p34=0;
  float p22=0,p23=0,p24=0,p13=0,p14=0,p04=0;
  if (active) {
    const float* r = tile + t * 25;
    p40=r[20]; p41=r[21]; p42=r[22]; p43=r[23]; p44=r[24];
    p31=r[16]; p32=r[17]; p33=r[18]; p34=r[19];
    p22=r[12]; p23=r[13]; p24=r[14];
    p13=r[8];  p14=r[9];
    p04=r[4];
  }
  __syncthreads();

  // ---------- stage mask tile ----------
  if (full) {
    const float4* src = (const float4*)(mask + blockRow * 25);
    float4* dst = (float4*)tile;
    #pragma unroll
    for (int k = 0; k < 7; ++k) {
      int i = k * 256 + t;
      if (i < TFLOATS / 4) dst[i] = src[i];
    }
  } else {
    const float* src = mask + blockRow * 25;
    int n = (int)((long long)B - blockRow) * 25;
    for (int i = t; i < n; i += 256) tile[i] = src[i];
  }
  __syncthreads();

  float m31=0, m22=0, m13=0, m04=0;
  if (active) {
    const float* r = tile + t * 25;
    m31=r[16]; m22=r[12]; m13=r[8]; m04=r[4];
  }
  __syncthreads();   // everyone done reading mask before tile is reused for outputs

  // ---------- compute ----------
  // p1: mask multiplies only the LAST product term (Python precedence)
  float p1_1 = p40 * p41 * m31;
  float p1_2 = p40 * p42 + p31 * p32 * m22;
  float p1_3 = p40 * p43 + p31 * p33 + p22 * p23 * m13;
  float p1_4 = p40 * p44 + p31 * p34 + p22 * p24 + p13 * p14 * m04;

  float q40 = 1.f - p40, q31 = 1.f - p31, q22 = 1.f - p22, q13 = 1.f - p13;
  float p2_1 = q31 * (1.f - q40) * m31;
  float p2_2 = q22 * (1.f - q40 * q31) * m22;
  float p2_3 = q13 * (1.f - q40 * q31 * q22) * m13;
  float p2_4 = (1.f - p04) * (1.f - q40 * q31 * q22 * q13) * m04;

  // ---------- stage outputs to LDS, then coalesced float4 stores ----------
  if (active) {
    float* o1 = tile + t * 5;                 // stride 5 -> 2-way alias, free
    o1[0]=0.f; o1[1]=p1_1; o1[2]=p1_2; o1[3]=p1_3; o1[4]=p1_4;
    float* o2 = tile + TILE * 5 + t * 5;
    o2[0]=0.f; o2[1]=p2_1; o2[2]=p2_2; o2[3]=p2_3; o2[4]=p2_4;
  }
  __syncthreads();

  long long base1 = blockRow * 5;
  long long base2 = (long long)B * 5 + blockRow * 5;
  bool aligned = (((size_t)out | (size_t)(base2 * 4)) & 15) == 0;  // base1*4 = 5120*bid, always aligned
  if (full && aligned) {
    float4* o1 = (float4*)(out + base1);
    float4* o2 = (float4*)(out + base2);
    const float4* s1 = (const float4*)tile;
    const float4* s2 = (const float4*)(tile + TILE * 5);
    #pragma unroll
    for (int k = 0; k < 2; ++k) {
      int i = k * 256 + t;
      if (i < TILE * 5 / 4) { o1[i] = s1[i]; o2[i] = s2[i]; }
    }
  } else {
    int n = full ? TILE * 5 : (int)((long long)B - blockRow) * 5;
    for (int i = t; i < n; i += 256) {
      out[base1 + i] = tile[i];
      out[base2 + i] = tile[TILE * 5 + i];
    }
  }
}

extern "C" void kernel_launch(void* const* d_in, const int* in_sizes, int n_in,
                              void* d_out, int out_size, void* d_ws, size_t ws_size,
                              hipStream_t stream) {
  const float* pred = (const float*)d_in[0];
  const float* mask = (const float*)d_in[1];
  float* out = (float*)d_out;
  int B = in_sizes[0] / 25;

  int blocks = (B + TILE - 1) / TILE;
  returning_rate_kernel<<<blocks, 256, 0, stream>>>(pred, mask, out, B);
}

// Round 3
// 97.316 us; speedup vs baseline: 1.0201x; 1.0201x over previous
//
#include <hip/hip_runtime.h>

__global__ __launch_bounds__(256) void returning_rate_kernel(
    const float* __restrict__ pred, const float* __restrict__ mask,
    float* __restrict__ out, int B) {
  int s = blockIdx.x * blockDim.x + threadIdx.x;
  if (s >= B) return;

  const float* pr = pred + (size_t)s * 25;
  const float* mk = mask + (size_t)s * 25;

  // Vector loads (dword-aligned dwordx4; gfx950 global loads need only 4B align)
  float4 a, b2, c, d, e;
  __builtin_memcpy(&a,  pr + 4,  16);  // 4,5,6,7
  __builtin_memcpy(&b2, pr + 8,  16);  // 8,9,10,11
  __builtin_memcpy(&c,  pr + 12, 16);  // 12,13,14,15
  __builtin_memcpy(&d,  pr + 16, 16);  // 16,17,18,19
  __builtin_memcpy(&e,  pr + 20, 16);  // 20,21,22,23
  float p44 = pr[24];
  float m04 = mk[4], m13 = mk[8], m22 = mk[12], m31 = mk[16];

  float p04 = a.x;
  float p13 = b2.x, p14 = b2.y;
  float p22 = c.x,  p23 = c.y,  p24 = c.z;
  float p31 = d.x,  p32 = d.y,  p33 = d.z, p34 = d.w;
  float p40 = e.x,  p41 = e.y,  p42 = e.z, p43 = e.w;

  // p1: mask multiplies only the LAST product term (Python precedence)
  float p1_1 = p40 * p41 * m31;
  float p1_2 = p40 * p42 + p31 * p32 * m22;
  float p1_3 = p40 * p43 + p31 * p33 + p22 * p23 * m13;
  float p1_4 = p40 * p44 + p31 * p34 + p22 * p24 + p13 * p14 * m04;

  float q40 = 1.f - p40, q31 = 1.f - p31, q22 = 1.f - p22, q13 = 1.f - p13;
  float p2_1 = q31 * (1.f - q40) * m31;
  float p2_2 = q22 * (1.f - q40 * q31) * m22;
  float p2_3 = q13 * (1.f - q40 * q31 * q22) * m13;
  float p2_4 = (1.f - p04) * (1.f - q40 * q31 * q22 * q13) * m04;

  // Non-temporal stores: outputs are never re-read this pass — keep them out
  // of L3 so the 256MB cache holds more of the 400MB input read-set.
  float* o1 = out + (size_t)s * 5;
  __builtin_nontemporal_store(0.f,  o1 + 0);
  __builtin_nontemporal_store(p1_1, o1 + 1);
  __builtin_nontemporal_store(p1_2, o1 + 2);
  __builtin_nontemporal_store(p1_3, o1 + 3);
  __builtin_nontemporal_store(p1_4, o1 + 4);
  float* o2 = out + (size_t)B * 5 + (size_t)s * 5;
  __builtin_nontemporal_store(0.f,  o2 + 0);
  __builtin_nontemporal_store(p2_1, o2 + 1);
  __builtin_nontemporal_store(p2_2, o2 + 2);
  __builtin_nontemporal_store(p2_3, o2 + 3);
  __builtin_nontemporal_store(p2_4, o2 + 4);
}

extern "C" void kernel_launch(void* const* d_in, const int* in_sizes, int n_in,
                              void* d_out, int out_size, void* d_ws, size_t ws_size,
                              hipStream_t stream) {
  const float* pred = (const float*)d_in[0];
  const float* mask = (const float*)d_in[1];
  float* out = (float*)d_out;
  int B = in_sizes[0] / 25;

  const int block = 256;
  int blocks = (B + block - 1) / block;
  returning_rate_kernel<<<blocks, block, 0, stream>>>(pred, mask, out, B);
}